// Round 1
// baseline (581.416 us; speedup 1.0000x reference)
//
#include <hip/hip_runtime.h>
#include <hip/hip_bf16.h>

// CrossAttention (bug-faithful: per-position attention across the 16 heads).
// Pipeline: 3x GEMM (x@W^T+b, bf16 MFMA) -> per-position head-softmax -> GEMM.
// GEMM: BM=BN=128, BK=64, 256 thr (4 waves, 2x2), mfma_f32_16x16x32_bf16,
// reg-staged fp32->bf16 conversion into XOR-swizzled LDS (byte ^= (row&7)<<4).

typedef __attribute__((ext_vector_type(8))) __bf16 bf16x8;
typedef __attribute__((ext_vector_type(4))) float f32x4;

#define BM 128
#define BN 128
#define BK 64

__device__ __forceinline__ float bf2f(ushort u) {
  union { unsigned int i; float f; } c; c.i = ((unsigned int)u) << 16; return c.f;
}
__device__ __forceinline__ ushort f2b(float f) {
  union { float f; unsigned int i; } c; c.f = f;
  unsigned int x = c.i;
  return (ushort)((x + 0x7FFFu + ((x >> 16) & 1u)) >> 16);  // RNE
}

// C[M][N] = A[M][K] @ B[N][K]^T + bias[N].  B (weights) always fp32 (out,in).
template<bool A_IS_BF16, bool OUT_BF16>
__global__ __launch_bounds__(256)
void gemm_bt(const void* __restrict__ Av, const float* __restrict__ B,
             const float* __restrict__ bias, void* __restrict__ Cv,
             int M, int N, int K)
{
  __shared__ ushort As[BM * BK];
  __shared__ ushort Bs[BN * BK];

  const int tid  = threadIdx.x;
  const int lane = tid & 63;
  const int wid  = tid >> 6;
  const int wr   = wid >> 1;        // wave row 0..1 (64 rows each)
  const int wc   = wid & 1;         // wave col 0..1 (64 cols each)
  const int m0   = blockIdx.y * BM;
  const int n0   = blockIdx.x * BN;

  f32x4 acc[4][4] = {};

  const int r   = tid >> 1;         // staging row 0..127
  const int seg = (tid & 1) * 32;   // k-offset 0 or 32 within tile

  for (int k0 = 0; k0 < K; k0 += BK) {
    // ---- stage A tile (128 x 64) ----
    {
      ushort tmp[32];
      if constexpr (A_IS_BF16) {
        const ushort* gA = (const ushort*)Av + (size_t)(m0 + r) * K + k0 + seg;
        #pragma unroll
        for (int u = 0; u < 4; ++u)
          *reinterpret_cast<uint4*>(&tmp[u * 8]) =
              *reinterpret_cast<const uint4*>(gA + u * 8);
      } else {
        const float* gA = (const float*)Av + (size_t)(m0 + r) * K + k0 + seg;
        #pragma unroll
        for (int u = 0; u < 8; ++u) {
          float4 f = *reinterpret_cast<const float4*>(gA + u * 4);
          tmp[u * 4 + 0] = f2b(f.x); tmp[u * 4 + 1] = f2b(f.y);
          tmp[u * 4 + 2] = f2b(f.z); tmp[u * 4 + 3] = f2b(f.w);
        }
      }
      #pragma unroll
      for (int s4 = 0; s4 < 4; ++s4) {
        int slot = (seg >> 3) + s4;                       // 16B slot 0..7
        int byte = r * 128 + ((slot ^ (r & 7)) << 4);     // XOR swizzle
        *reinterpret_cast<uint4*>((char*)As + byte) =
            *reinterpret_cast<uint4*>(&tmp[s4 * 8]);
      }
    }
    // ---- stage B tile (128 x 64), fp32 weights ----
    {
      const float* gB = B + (size_t)(n0 + r) * K + k0 + seg;
      ushort tmp[32];
      #pragma unroll
      for (int u = 0; u < 8; ++u) {
        float4 f = *reinterpret_cast<const float4*>(gB + u * 4);
        tmp[u * 4 + 0] = f2b(f.x); tmp[u * 4 + 1] = f2b(f.y);
        tmp[u * 4 + 2] = f2b(f.z); tmp[u * 4 + 3] = f2b(f.w);
      }
      #pragma unroll
      for (int s4 = 0; s4 < 4; ++s4) {
        int slot = (seg >> 3) + s4;
        int byte = r * 128 + ((slot ^ (r & 7)) << 4);
        *reinterpret_cast<uint4*>((char*)Bs + byte) =
            *reinterpret_cast<uint4*>(&tmp[s4 * 8]);
      }
    }
    __syncthreads();

    #pragma unroll
    for (int kk = 0; kk < 2; ++kk) {
      const int kbase = kk * 32 + ((lane >> 4) << 3);  // lane's 8-contig k base
      const int slot  = kbase >> 3;
      bf16x8 af[4], bfr[4];
      #pragma unroll
      for (int mi = 0; mi < 4; ++mi) {
        int row = wr * 64 + mi * 16 + (lane & 15);
        af[mi] = *reinterpret_cast<const bf16x8*>(
            (const char*)As + row * 128 + ((slot ^ (row & 7)) << 4));
      }
      #pragma unroll
      for (int ni = 0; ni < 4; ++ni) {
        int row = wc * 64 + ni * 16 + (lane & 15);
        bfr[ni] = *reinterpret_cast<const bf16x8*>(
            (const char*)Bs + row * 128 + ((slot ^ (row & 7)) << 4));
      }
      #pragma unroll
      for (int mi = 0; mi < 4; ++mi)
        #pragma unroll
        for (int ni = 0; ni < 4; ++ni)
          acc[mi][ni] = __builtin_amdgcn_mfma_f32_16x16x32_bf16(
              af[mi], bfr[ni], acc[mi][ni], 0, 0, 0);
    }
    __syncthreads();
  }

  // epilogue: +bias, store (C/D layout: col=lane&15, row=(lane>>4)*4+q)
  #pragma unroll
  for (int ni = 0; ni < 4; ++ni) {
    int col = n0 + wc * 64 + ni * 16 + (lane & 15);
    float bv = bias[col];
    #pragma unroll
    for (int mi = 0; mi < 4; ++mi) {
      int row0 = m0 + wr * 64 + mi * 16 + ((lane >> 4) << 2);
      #pragma unroll
      for (int q = 0; q < 4; ++q) {
        float v = acc[mi][ni][q] + bv;
        if constexpr (OUT_BF16)
          ((ushort*)Cv)[(size_t)(row0 + q) * N + col] = f2b(v);
        else
          ((float*)Cv)[(size_t)(row0 + q) * N + col] = v;
      }
    }
  }
}

// Per-position attention across heads. One wave per position.
// lane -> (i = lane>>2 out-head, jg = lane&3 j-group of 4); softmax over 16 j.
__global__ __launch_bounds__(256)
void attn_kernel(const ushort* __restrict__ Q, const ushort* __restrict__ Kh,
                 const ushort* __restrict__ V, ushort* __restrict__ O)
{
  __shared__ float smem[4][3][16][68];   // [wave][Q/K/V][head][64+pad]
  const int tid  = threadIdx.x;
  const int wid  = tid >> 6;
  const int lane = tid & 63;
  const size_t p = (size_t)blockIdx.x * 4 + wid;

  {
    const ushort* srcs[3] = { Q + p * 1024, Kh + p * 1024, V + p * 1024 };
    const int i  = lane >> 2;
    const int d0 = (lane & 3) * 16;
    #pragma unroll
    for (int m = 0; m < 3; ++m) {
      const ushort* s = srcs[m] + lane * 16;
      ushort u[16];
      *reinterpret_cast<uint4*>(&u[0]) = *reinterpret_cast<const uint4*>(s);
      *reinterpret_cast<uint4*>(&u[8]) = *reinterpret_cast<const uint4*>(s + 8);
      #pragma unroll
      for (int e = 0; e < 16; ++e) smem[wid][m][i][d0 + e] = bf2f(u[e]);
    }
  }
  __syncthreads();

  const int i  = lane >> 2;
  const int jg = lane & 3;
  const float* qrow = smem[wid][0][i];
  const float* k0r = smem[wid][1][jg * 4 + 0];
  const float* k1r = smem[wid][1][jg * 4 + 1];
  const float* k2r = smem[wid][1][jg * 4 + 2];
  const float* k3r = smem[wid][1][jg * 4 + 3];

  float s0 = 0.f, s1 = 0.f, s2 = 0.f, s3 = 0.f;
  #pragma unroll
  for (int d = 0; d < 64; ++d) {
    float qv = qrow[d];
    s0 += qv * k0r[d]; s1 += qv * k1r[d];
    s2 += qv * k2r[d]; s3 += qv * k3r[d];
  }
  const float scale = 0.125f;  // 1/sqrt(64)
  s0 *= scale; s1 *= scale; s2 *= scale; s3 *= scale;

  float mx = fmaxf(fmaxf(s0, s1), fmaxf(s2, s3));
  mx = fmaxf(mx, __shfl_xor(mx, 1));
  mx = fmaxf(mx, __shfl_xor(mx, 2));
  float e0 = __expf(s0 - mx), e1 = __expf(s1 - mx);
  float e2 = __expf(s2 - mx), e3 = __expf(s3 - mx);
  float sum = e0 + e1 + e2 + e3;
  sum += __shfl_xor(sum, 1);
  sum += __shfl_xor(sum, 2);
  float inv = 1.0f / sum;
  e0 *= inv; e1 *= inv; e2 *= inv; e3 *= inv;

  const float* v0r = smem[wid][2][jg * 4 + 0];
  const float* v1r = smem[wid][2][jg * 4 + 1];
  const float* v2r = smem[wid][2][jg * 4 + 2];
  const float* v3r = smem[wid][2][jg * 4 + 3];
  ushort* orow = O + p * 1024 + i * 64;

  #pragma unroll
  for (int c = 0; c < 4; ++c) {
    float po[16];
    #pragma unroll
    for (int dd = 0; dd < 16; ++dd) {
      int d = c * 16 + dd;
      po[dd] = e0 * v0r[d] + e1 * v1r[d] + e2 * v2r[d] + e3 * v3r[d];
    }
    #pragma unroll
    for (int dd = 0; dd < 16; ++dd) {
      po[dd] += __shfl_xor(po[dd], 1);
      po[dd] += __shfl_xor(po[dd], 2);
    }
    if (jg == c) {
      #pragma unroll
      for (int dd = 0; dd < 16; ++dd) orow[c * 16 + dd] = f2b(po[dd]);
    }
  }
}

extern "C" void kernel_launch(void* const* d_in, const int* in_sizes, int n_in,
                              void* d_out, int out_size, void* d_ws, size_t ws_size,
                              hipStream_t stream)
{
  const float* query = (const float*)d_in[0];
  const float* key_  = (const float*)d_in[1];
  const float* value = (const float*)d_in[2];
  const float* wq_w  = (const float*)d_in[3];
  const float* wq_b  = (const float*)d_in[4];
  const float* wk_w  = (const float*)d_in[5];
  const float* wk_b  = (const float*)d_in[6];
  const float* wv_w  = (const float*)d_in[7];
  const float* wv_b  = (const float*)d_in[8];
  const float* fo_w  = (const float*)d_in[9];
  const float* fo_b  = (const float*)d_in[10];

  const int K = 1024, N = 1024;
  const int M = in_sizes[0] / K;   // 8*2048 = 16384

  // workspace: Q,K,V,O in bf16 (4 x M*N*2B = 128 MB)
  ushort* Qb = (ushort*)d_ws;
  ushort* Kb = Qb + (size_t)M * N;
  ushort* Vb = Kb + (size_t)M * N;
  ushort* Ob = Vb + (size_t)M * N;

  dim3 grid(N / BN, M / BM);
  gemm_bt<false, true><<<grid, dim3(256), 0, stream>>>(query, wq_w, wq_b, Qb, M, N, K);
  gemm_bt<false, true><<<grid, dim3(256), 0, stream>>>(key_,  wk_w, wk_b, Kb, M, N, K);
  gemm_bt<false, true><<<grid, dim3(256), 0, stream>>>(value, wv_w, wv_b, Vb, M, N, K);
  attn_kernel<<<dim3(M / 4), dim3(256), 0, stream>>>(Qb, Kb, Vb, Ob);
  gemm_bt<true, false><<<grid, dim3(256), 0, stream>>>(Ob, fo_w, fo_b, d_out, M, N, K);
}

// Round 2
// 368.027 us; speedup vs baseline: 1.5798x; 1.5798x over previous
//
#include <hip/hip_runtime.h>
#include <hip/hip_bf16.h>

// CrossAttention (bug-faithful: per-position attention across the 16 heads).
// Round 2: convert-once fp32->bf16, then 4x pure-bf16 GEMM (m97 structure:
// global_load_lds width-16 staging, linear LDS, 128x128x64 tile, 4 waves 2x2,
// mfma_f32_16x16x32_bf16) -> per-position head-softmax -> GEMM -> fp32 out.
// Fallback to round-1 reg-staged path if ws_size < 136 MiB.

typedef __attribute__((ext_vector_type(8))) __bf16 bf16x8;
typedef __attribute__((ext_vector_type(4))) float f32x4;

#define BM 128
#define BN 128
#define BK 64

__device__ __forceinline__ float bf2f(ushort u) {
  union { unsigned int i; float f; } c; c.i = ((unsigned int)u) << 16; return c.f;
}
__device__ __forceinline__ ushort f2b(float f) {
  union { float f; unsigned int i; } c; c.f = f;
  unsigned int x = c.i;
  return (ushort)((x + 0x7FFFu + ((x >> 16) & 1u)) >> 16);  // RNE
}

// ---------------- fp32 -> bf16 convert (vectorized, 8 elems/thread) --------
__global__ __launch_bounds__(256)
void cvt_f32_bf16(const float* __restrict__ s, ushort* __restrict__ d, int n8)
{
  int i = blockIdx.x * 256 + threadIdx.x;
  if (i >= n8) return;
  const float4* sp = reinterpret_cast<const float4*>(s) + (size_t)i * 2;
  float4 a = sp[0], b = sp[1];
  ushort u[8] = { f2b(a.x), f2b(a.y), f2b(a.z), f2b(a.w),
                  f2b(b.x), f2b(b.y), f2b(b.z), f2b(b.w) };
  reinterpret_cast<uint4*>(d)[i] = *reinterpret_cast<uint4*>(u);
}

// ---------------- bf16 GEMM, C = A[M][K] @ B[N][K]^T + bias[N] -------------
// m97 structure: global_load_lds dwordx4 staging, linear LDS, 2-barrier loop.
template<bool OUT_BF16>
__global__ __launch_bounds__(256)
void gemm_bb(const ushort* __restrict__ A, const ushort* __restrict__ Bw,
             const float* __restrict__ bias, void* __restrict__ Cv,
             int M, int N, int K)
{
  __shared__ ushort As[BM * BK];
  __shared__ ushort Bs[BN * BK];

  const int tid  = threadIdx.x;
  const int lane = tid & 63;
  const int wid  = tid >> 6;
  const int wr   = wid >> 1;
  const int wc   = wid & 1;
  const int m0   = blockIdx.y * BM;
  const int n0   = blockIdx.x * BN;

  f32x4 acc[4][4] = {};

  // staging geometry: wave w, issue u covers LDS bytes [w*1024 + u*4096, +1024)
  // lane writes 16B at base + lane*16 (HW adds lane offset); element
  // e = w*512 + u*2048 + lane*8 -> row = e>>6, col = e&63 of the 128x64 tile.
  const int eb = wid * 512 + lane * 8;
  const ushort* gA = A + (size_t)m0 * K;
  const ushort* gB = Bw + (size_t)n0 * K;

  for (int k0 = 0; k0 < K; k0 += BK) {
    #pragma unroll
    for (int u = 0; u < 4; ++u) {
      int e = eb + u * 2048;
      int row = e >> 6, col = e & 63;
      __builtin_amdgcn_global_load_lds(
          (const __attribute__((address_space(1))) void*)(gA + (size_t)row * K + k0 + col),
          (__attribute__((address_space(3))) void*)(As + wid * 512 + u * 2048),
          16, 0, 0);
    }
    #pragma unroll
    for (int u = 0; u < 4; ++u) {
      int e = eb + u * 2048;
      int row = e >> 6, col = e & 63;
      __builtin_amdgcn_global_load_lds(
          (const __attribute__((address_space(1))) void*)(gB + (size_t)row * K + k0 + col),
          (__attribute__((address_space(3))) void*)(Bs + wid * 512 + u * 2048),
          16, 0, 0);
    }
    __syncthreads();

    #pragma unroll
    for (int kk = 0; kk < 2; ++kk) {
      const int kb = kk * 32 + ((lane >> 4) << 3);
      bf16x8 af[4], bfr[4];
      #pragma unroll
      for (int mi = 0; mi < 4; ++mi)
        af[mi] = *reinterpret_cast<const bf16x8*>(
            &As[(wr * 64 + mi * 16 + (lane & 15)) * BK + kb]);
      #pragma unroll
      for (int ni = 0; ni < 4; ++ni)
        bfr[ni] = *reinterpret_cast<const bf16x8*>(
            &Bs[(wc * 64 + ni * 16 + (lane & 15)) * BK + kb]);
      #pragma unroll
      for (int mi = 0; mi < 4; ++mi)
        #pragma unroll
        for (int ni = 0; ni < 4; ++ni)
          acc[mi][ni] = __builtin_amdgcn_mfma_f32_16x16x32_bf16(
              af[mi], bfr[ni], acc[mi][ni], 0, 0, 0);
    }
    __syncthreads();
  }

  // epilogue: +bias, store (C/D layout: col=lane&15, row=(lane>>4)*4+q)
  #pragma unroll
  for (int ni = 0; ni < 4; ++ni) {
    int col = n0 + wc * 64 + ni * 16 + (lane & 15);
    float bv = bias[col];
    #pragma unroll
    for (int mi = 0; mi < 4; ++mi) {
      int row0 = m0 + wr * 64 + mi * 16 + ((lane >> 4) << 2);
      #pragma unroll
      for (int q = 0; q < 4; ++q) {
        float v = acc[mi][ni][q] + bv;
        if constexpr (OUT_BF16)
          ((ushort*)Cv)[(size_t)(row0 + q) * N + col] = f2b(v);
        else
          ((float*)Cv)[(size_t)(row0 + q) * N + col] = v;
      }
    }
  }
}

// --------- fallback GEMM (round-1, fp32 reg-staged, XOR-swizzled LDS) ------
template<bool A_IS_BF16, bool OUT_BF16>
__global__ __launch_bounds__(256)
void gemm_bt(const void* __restrict__ Av, const float* __restrict__ B,
             const float* __restrict__ bias, void* __restrict__ Cv,
             int M, int N, int K)
{
  __shared__ ushort As[BM * BK];
  __shared__ ushort Bs[BN * BK];

  const int tid  = threadIdx.x;
  const int lane = tid & 63;
  const int wid  = tid >> 6;
  const int wr   = wid >> 1;
  const int wc   = wid & 1;
  const int m0   = blockIdx.y * BM;
  const int n0   = blockIdx.x * BN;

  f32x4 acc[4][4] = {};

  const int r   = tid >> 1;
  const int seg = (tid & 1) * 32;

  for (int k0 = 0; k0 < K; k0 += BK) {
    {
      ushort tmp[32];
      if constexpr (A_IS_BF16) {
        const ushort* gA = (const ushort*)Av + (size_t)(m0 + r) * K + k0 + seg;
        #pragma unroll
        for (int u = 0; u < 4; ++u)
          *reinterpret_cast<uint4*>(&tmp[u * 8]) =
              *reinterpret_cast<const uint4*>(gA + u * 8);
      } else {
        const float* gA = (const float*)Av + (size_t)(m0 + r) * K + k0 + seg;
        #pragma unroll
        for (int u = 0; u < 8; ++u) {
          float4 f = *reinterpret_cast<const float4*>(gA + u * 4);
          tmp[u * 4 + 0] = f2b(f.x); tmp[u * 4 + 1] = f2b(f.y);
          tmp[u * 4 + 2] = f2b(f.z); tmp[u * 4 + 3] = f2b(f.w);
        }
      }
      #pragma unroll
      for (int s4 = 0; s4 < 4; ++s4) {
        int slot = (seg >> 3) + s4;
        int byte = r * 128 + ((slot ^ (r & 7)) << 4);
        *reinterpret_cast<uint4*>((char*)As + byte) =
            *reinterpret_cast<uint4*>(&tmp[s4 * 8]);
      }
    }
    {
      const float* gB = B + (size_t)(n0 + r) * K + k0 + seg;
      ushort tmp[32];
      #pragma unroll
      for (int u = 0; u < 8; ++u) {
        float4 f = *reinterpret_cast<const float4*>(gB + u * 4);
        tmp[u * 4 + 0] = f2b(f.x); tmp[u * 4 + 1] = f2b(f.y);
        tmp[u * 4 + 2] = f2b(f.z); tmp[u * 4 + 3] = f2b(f.w);
      }
      #pragma unroll
      for (int s4 = 0; s4 < 4; ++s4) {
        int slot = (seg >> 3) + s4;
        int byte = r * 128 + ((slot ^ (r & 7)) << 4);
        *reinterpret_cast<uint4*>((char*)Bs + byte) =
            *reinterpret_cast<uint4*>(&tmp[s4 * 8]);
      }
    }
    __syncthreads();

    #pragma unroll
    for (int kk = 0; kk < 2; ++kk) {
      const int kbase = kk * 32 + ((lane >> 4) << 3);
      const int slot  = kbase >> 3;
      bf16x8 af[4], bfr[4];
      #pragma unroll
      for (int mi = 0; mi < 4; ++mi) {
        int row = wr * 64 + mi * 16 + (lane & 15);
        af[mi] = *reinterpret_cast<const bf16x8*>(
            (const char*)As + row * 128 + ((slot ^ (row & 7)) << 4));
      }
      #pragma unroll
      for (int ni = 0; ni < 4; ++ni) {
        int row = wc * 64 + ni * 16 + (lane & 15);
        bfr[ni] = *reinterpret_cast<const bf16x8*>(
            (const char*)Bs + row * 128 + ((slot ^ (row & 7)) << 4));
      }
      #pragma unroll
      for (int mi = 0; mi < 4; ++mi)
        #pragma unroll
        for (int ni = 0; ni < 4; ++ni)
          acc[mi][ni] = __builtin_amdgcn_mfma_f32_16x16x32_bf16(
              af[mi], bfr[ni], acc[mi][ni], 0, 0, 0);
    }
    __syncthreads();
  }

  #pragma unroll
  for (int ni = 0; ni < 4; ++ni) {
    int col = n0 + wc * 64 + ni * 16 + (lane & 15);
    float bv = bias[col];
    #pragma unroll
    for (int mi = 0; mi < 4; ++mi) {
      int row0 = m0 + wr * 64 + mi * 16 + ((lane >> 4) << 2);
      #pragma unroll
      for (int q = 0; q < 4; ++q) {
        float v = acc[mi][ni][q] + bv;
        if constexpr (OUT_BF16)
          ((ushort*)Cv)[(size_t)(row0 + q) * N + col] = f2b(v);
        else
          ((float*)Cv)[(size_t)(row0 + q) * N + col] = v;
      }
    }
  }
}

// ---------------- per-position attention across heads ----------------------
__global__ __launch_bounds__(256)
void attn_kernel(const ushort* __restrict__ Q, const ushort* __restrict__ Kh,
                 const ushort* __restrict__ V, ushort* __restrict__ O)
{
  __shared__ float smem[4][3][16][68];   // [wave][Q/K/V][head][64+pad]
  const int tid  = threadIdx.x;
  const int wid  = tid >> 6;
  const int lane = tid & 63;
  const size_t p = (size_t)blockIdx.x * 4 + wid;

  {
    const ushort* srcs[3] = { Q + p * 1024, Kh + p * 1024, V + p * 1024 };
    const int i  = lane >> 2;
    const int d0 = (lane & 3) * 16;
    #pragma unroll
    for (int m = 0; m < 3; ++m) {
      const ushort* s = srcs[m] + lane * 16;
      ushort u[16];
      *reinterpret_cast<uint4*>(&u[0]) = *reinterpret_cast<const uint4*>(s);
      *reinterpret_cast<uint4*>(&u[8]) = *reinterpret_cast<const uint4*>(s + 8);
      #pragma unroll
      for (int e = 0; e < 16; ++e) smem[wid][m][i][d0 + e] = bf2f(u[e]);
    }
  }
  __syncthreads();

  const int i  = lane >> 2;
  const int jg = lane & 3;
  const float* qrow = smem[wid][0][i];
  const float* k0r = smem[wid][1][jg * 4 + 0];
  const float* k1r = smem[wid][1][jg * 4 + 1];
  const float* k2r = smem[wid][1][jg * 4 + 2];
  const float* k3r = smem[wid][1][jg * 4 + 3];

  float s0 = 0.f, s1 = 0.f, s2 = 0.f, s3 = 0.f;
  #pragma unroll
  for (int d = 0; d < 64; ++d) {
    float qv = qrow[d];
    s0 += qv * k0r[d]; s1 += qv * k1r[d];
    s2 += qv * k2r[d]; s3 += qv * k3r[d];
  }
  const float scale = 0.125f;  // 1/sqrt(64)
  s0 *= scale; s1 *= scale; s2 *= scale; s3 *= scale;

  float mx = fmaxf(fmaxf(s0, s1), fmaxf(s2, s3));
  mx = fmaxf(mx, __shfl_xor(mx, 1));
  mx = fmaxf(mx, __shfl_xor(mx, 2));
  float e0 = __expf(s0 - mx), e1 = __expf(s1 - mx);
  float e2 = __expf(s2 - mx), e3 = __expf(s3 - mx);
  float sum = e0 + e1 + e2 + e3;
  sum += __shfl_xor(sum, 1);
  sum += __shfl_xor(sum, 2);
  float inv = 1.0f / sum;
  e0 *= inv; e1 *= inv; e2 *= inv; e3 *= inv;

  const float* v0r = smem[wid][2][jg * 4 + 0];
  const float* v1r = smem[wid][2][jg * 4 + 1];
  const float* v2r = smem[wid][2][jg * 4 + 2];
  const float* v3r = smem[wid][2][jg * 4 + 3];
  ushort* orow = O + p * 1024 + i * 64;

  #pragma unroll
  for (int c = 0; c < 4; ++c) {
    float po[16];
    #pragma unroll
    for (int dd = 0; dd < 16; ++dd) {
      int d = c * 16 + dd;
      po[dd] = e0 * v0r[d] + e1 * v1r[d] + e2 * v2r[d] + e3 * v3r[d];
    }
    #pragma unroll
    for (int dd = 0; dd < 16; ++dd) {
      po[dd] += __shfl_xor(po[dd], 1);
      po[dd] += __shfl_xor(po[dd], 2);
    }
    if (jg == c) {
      #pragma unroll
      for (int dd = 0; dd < 16; ++dd) orow[c * 16 + dd] = f2b(po[dd]);
    }
  }
}

extern "C" void kernel_launch(void* const* d_in, const int* in_sizes, int n_in,
                              void* d_out, int out_size, void* d_ws, size_t ws_size,
                              hipStream_t stream)
{
  const float* query = (const float*)d_in[0];
  const float* key_  = (const float*)d_in[1];
  const float* value = (const float*)d_in[2];
  const float* wq_w  = (const float*)d_in[3];
  const float* wq_b  = (const float*)d_in[4];
  const float* wk_w  = (const float*)d_in[5];
  const float* wk_b  = (const float*)d_in[6];
  const float* wv_w  = (const float*)d_in[7];
  const float* wv_b  = (const float*)d_in[8];
  const float* fo_w  = (const float*)d_in[9];
  const float* fo_b  = (const float*)d_in[10];

  const int K = 1024, N = 1024;
  const int M = in_sizes[0] / K;       // 16384
  const size_t slot = (size_t)M * N;   // elements per big slot
  const size_t wsl  = (size_t)N * K;   // elements per weight
  const size_t need = (4 * slot + 4 * wsl) * sizeof(ushort);  // 136 MiB

  dim3 grid(N / BN, M / BM);

  if (ws_size >= need) {
    // new path: convert-once + pure-bf16 DMA-staged GEMMs
    ushort* S0 = (ushort*)d_ws;           // recycled input slot, then attn out
    ushort* S1 = S0 + slot;               // Q projection
    ushort* S2 = S1 + slot;               // K projection
    ushort* S3 = S2 + slot;               // V projection
    ushort* Wq = S3 + slot;
    ushort* Wk = Wq + wsl;
    ushort* Wv = Wk + wsl;
    ushort* Wo = Wv + wsl;

    const int n8w = (int)(wsl / 8);       // 131072 -> 512 blocks
    const int n8s = (int)(slot / 8);      // 2097152 -> 8192 blocks
    cvt_f32_bf16<<<dim3((n8w + 255) / 256), dim3(256), 0, stream>>>(wq_w, Wq, n8w);
    cvt_f32_bf16<<<dim3((n8w + 255) / 256), dim3(256), 0, stream>>>(wk_w, Wk, n8w);
    cvt_f32_bf16<<<dim3((n8w + 255) / 256), dim3(256), 0, stream>>>(wv_w, Wv, n8w);
    cvt_f32_bf16<<<dim3((n8w + 255) / 256), dim3(256), 0, stream>>>(fo_w, Wo, n8w);

    cvt_f32_bf16<<<dim3((n8s + 255) / 256), dim3(256), 0, stream>>>(query, S0, n8s);
    gemm_bb<true><<<grid, dim3(256), 0, stream>>>(S0, Wq, wq_b, S1, M, N, K);
    cvt_f32_bf16<<<dim3((n8s + 255) / 256), dim3(256), 0, stream>>>(key_, S0, n8s);
    gemm_bb<true><<<grid, dim3(256), 0, stream>>>(S0, Wk, wk_b, S2, M, N, K);
    cvt_f32_bf16<<<dim3((n8s + 255) / 256), dim3(256), 0, stream>>>(value, S0, n8s);
    gemm_bb<true><<<grid, dim3(256), 0, stream>>>(S0, Wv, wv_b, S3, M, N, K);

    attn_kernel<<<dim3(M / 4), dim3(256), 0, stream>>>(S1, S2, S3, S0);
    gemm_bb<false><<<grid, dim3(256), 0, stream>>>(S0, Wo, fo_b, d_out, M, N, K);
  } else {
    // fallback: round-1 proven path (needs 128 MiB)
    ushort* Qb = (ushort*)d_ws;
    ushort* Kb = Qb + slot;
    ushort* Vb = Kb + slot;
    ushort* Ob = Vb + slot;
    gemm_bt<false, true><<<grid, dim3(256), 0, stream>>>(query, wq_w, wq_b, Qb, M, N, K);
    gemm_bt<false, true><<<grid, dim3(256), 0, stream>>>(key_,  wk_w, wk_b, Kb, M, N, K);
    gemm_bt<false, true><<<grid, dim3(256), 0, stream>>>(value, wv_w, wv_b, Vb, M, N, K);
    attn_kernel<<<dim3(M / 4), dim3(256), 0, stream>>>(Qb, Kb, Vb, Ob);
    gemm_bt<true, false><<<grid, dim3(256), 0, stream>>>(Ob, fo_w, fo_b, d_out, M, N, K);
  }
}

// Round 3
// 271.968 us; speedup vs baseline: 2.1378x; 1.3532x over previous
//
#include <hip/hip_runtime.h>
#include <hip/hip_bf16.h>

// CrossAttention (bug-faithful: per-position attention across the 16 heads).
// Round 3: 8-phase 256^2 counted-vmcnt GEMM (T2+T3+T4+T5 per m201 template),
// convert-once fp32->bf16, per-position head-softmax, fallback = round-1 path.

typedef __attribute__((ext_vector_type(8))) __bf16 bf16x8;
typedef __attribute__((ext_vector_type(4))) float f32x4;

#define BM 128
#define BN 128
#define BK 64

__device__ __forceinline__ float bf2f(ushort u) {
  union { unsigned int i; float f; } c; c.i = ((unsigned int)u) << 16; return c.f;
}
__device__ __forceinline__ ushort f2b(float f) {
  union { float f; unsigned int i; } c; c.f = f;
  unsigned int x = c.i;
  return (ushort)((x + 0x7FFFu + ((x >> 16) & 1u)) >> 16);  // RNE
}

// ---------------- fp32 -> bf16 convert (vectorized, 8 elems/thread) --------
__global__ __launch_bounds__(256)
void cvt_f32_bf16(const float* __restrict__ s, ushort* __restrict__ d, int n8)
{
  int i = blockIdx.x * 256 + threadIdx.x;
  if (i >= n8) return;
  const float4* sp = reinterpret_cast<const float4*>(s) + (size_t)i * 2;
  float4 a = sp[0], b = sp[1];
  ushort u[8] = { f2b(a.x), f2b(a.y), f2b(a.z), f2b(a.w),
                  f2b(b.x), f2b(b.y), f2b(b.z), f2b(b.w) };
  reinterpret_cast<uint4*>(d)[i] = *reinterpret_cast<uint4*>(u);
}

// ---------- 8-phase 256x256x64 bf16 GEMM: C = A @ B^T + bias ---------------
// 512 thr = 8 waves (2 wm x 4 wn). Per-wave C: 8x4 frags of 16x16, split so
// phase p = (A-half x B-half) quadrant. Double-buffered swizzled LDS 128 KiB.
// vmcnt(4) counted guards; stage order H0(A-lo),H2(B-lo),H3(B-hi),H1(A-hi).
template<bool OUT_BF16>
__global__ __launch_bounds__(512, 2)
void gemm8p(const ushort* __restrict__ A, const ushort* __restrict__ Bw,
            const float* __restrict__ bias, void* __restrict__ Cv,
            int M, int N, int K)
{
  extern __shared__ ushort lds[];   // [2 buf][A:16384 | B:16384] ushorts

  const int tid  = threadIdx.x;
  const int lane = tid & 63;
  const int wid  = tid >> 6;         // 0..7
  const int wm   = wid >> 2;         // 0..1
  const int wn   = wid & 3;          // 0..3

  // bijective XCD swizzle (nwg = 256, %8 == 0)
  const int nwg = gridDim.x * gridDim.y;
  int fid = blockIdx.y * gridDim.x + blockIdx.x;
  if ((nwg & 7) == 0) fid = (fid & 7) * (nwg >> 3) + (fid >> 3);
  const int bx = fid % gridDim.x;
  const int by = fid / gridDim.x;
  const int m0 = by * 256, n0 = bx * 256;

  const int NT = K >> 6;

  // stage half h of k-tile kt into buffer b. h: 0=A-lo,1=A-hi,2=B-lo,3=B-hi.
  // linear LDS dest + inverse-swizzled global source (rule 21).
  const int csw = ((lane & 7) ^ (lane >> 3)) << 3;   // pre-swizzled col offset
  auto STAGE = [&](int h, int kt, int b) {
    const ushort* base = (h >= 2) ? Bw : A;
    const int o0 = (h >= 2) ? n0 : m0;
    const int rl = (h & 1) * 128;
    #pragma unroll
    for (int j = 0; j < 2; ++j) {
      int rt = rl + j * 64 + wid * 8;
      const ushort* src = base + (size_t)(o0 + rt + (lane >> 3)) * K + kt * 64 + csw;
      ushort* dst = lds + b * 32768 + (h >= 2 ? 16384 : 0) + rt * 64;
      __builtin_amdgcn_global_load_lds(
          (const __attribute__((address_space(1))) void*)src,
          (__attribute__((address_space(3))) void*)dst, 16, 0, 0);
    }
  };

  // swizzled ds_read of one 16x16x32 fragment (kk = k-step 0/1)
  auto LDA = [&](int b, int mi, int kk) -> bf16x8 {
    int row  = (mi & 3) * 16 + wm * 64 + (mi >> 2) * 128 + (lane & 15);
    int slot = kk * 4 + (lane >> 4);
    int byte = row * 128 + (((slot ^ (row & 7)) & 7) << 4);
    return *reinterpret_cast<const bf16x8*>((const char*)(lds + b * 32768) + byte);
  };
  auto LDB = [&](int b, int ni, int kk) -> bf16x8 {
    int row  = (ni & 1) * 16 + wn * 32 + (ni >> 1) * 128 + (lane & 15);
    int slot = kk * 4 + (lane >> 4);
    int byte = row * 128 + (((slot ^ (row & 7)) & 7) << 4);
    return *reinterpret_cast<const bf16x8*>((const char*)(lds + b * 32768 + 16384) + byte);
  };

  f32x4 acc[8][4] = {};
  bf16x8 af[4][2], bf[4][2];

  // prologue: stage tile 0 (order H0,H2,H3,H1), guard oldest 4, barrier
  STAGE(0, 0, 0); STAGE(2, 0, 0); STAGE(3, 0, 0); STAGE(1, 0, 0);
  asm volatile("s_waitcnt vmcnt(4)" ::: "memory");
  __builtin_amdgcn_s_barrier();

  for (int t = 0; t < NT; ++t) {
    const int cur = t & 1;
    const int nxt = cur ^ 1;
    const bool pf = (t + 1) < NT;

    // ---- P0: (A-lo x B-lo). reads: A m0-3, B n0-1 ----
    #pragma unroll
    for (int i = 0; i < 4; ++i) { af[i][0] = LDA(cur, i, 0); af[i][1] = LDA(cur, i, 1); }
    #pragma unroll
    for (int n = 0; n < 2; ++n) { bf[n][0] = LDB(cur, n, 0); bf[n][1] = LDB(cur, n, 1); }
    if (pf) { STAGE(0, t + 1, nxt); asm volatile("s_waitcnt vmcnt(4)" ::: "memory"); }
    else    {                       asm volatile("s_waitcnt vmcnt(2)" ::: "memory"); }
    __builtin_amdgcn_s_barrier();
    asm volatile("s_waitcnt lgkmcnt(0)" ::: "memory");
    __builtin_amdgcn_sched_barrier(0);
    __builtin_amdgcn_s_setprio(1);
    #pragma unroll
    for (int i = 0; i < 4; ++i)
      #pragma unroll
      for (int n = 0; n < 2; ++n)
        #pragma unroll
        for (int kk = 0; kk < 2; ++kk)
          acc[i][n] = __builtin_amdgcn_mfma_f32_16x16x32_bf16(af[i][kk], bf[n][kk], acc[i][n], 0, 0, 0);
    __builtin_amdgcn_s_setprio(0);
    __builtin_amdgcn_s_barrier();

    // ---- P1: (A-lo x B-hi). reads: B n2-3 ----
    #pragma unroll
    for (int n = 0; n < 2; ++n) { bf[2 + n][0] = LDB(cur, 2 + n, 0); bf[2 + n][1] = LDB(cur, 2 + n, 1); }
    if (pf) { STAGE(2, t + 1, nxt); asm volatile("s_waitcnt vmcnt(4)" ::: "memory"); }
    else    {                       asm volatile("s_waitcnt vmcnt(0)" ::: "memory"); }
    __builtin_amdgcn_s_barrier();
    asm volatile("s_waitcnt lgkmcnt(0)" ::: "memory");
    __builtin_amdgcn_sched_barrier(0);
    __builtin_amdgcn_s_setprio(1);
    #pragma unroll
    for (int i = 0; i < 4; ++i)
      #pragma unroll
      for (int n = 0; n < 2; ++n)
        #pragma unroll
        for (int kk = 0; kk < 2; ++kk)
          acc[i][2 + n] = __builtin_amdgcn_mfma_f32_16x16x32_bf16(af[i][kk], bf[2 + n][kk], acc[i][2 + n], 0, 0, 0);
    __builtin_amdgcn_s_setprio(0);
    __builtin_amdgcn_s_barrier();

    // ---- P2: (A-hi x B-lo). reads: A m4-7. no vmcnt guard needed ----
    #pragma unroll
    for (int i = 0; i < 4; ++i) { af[i][0] = LDA(cur, 4 + i, 0); af[i][1] = LDA(cur, 4 + i, 1); }
    if (pf) STAGE(3, t + 1, nxt);
    __builtin_amdgcn_s_barrier();
    asm volatile("s_waitcnt lgkmcnt(0)" ::: "memory");
    __builtin_amdgcn_sched_barrier(0);
    __builtin_amdgcn_s_setprio(1);
    #pragma unroll
    for (int i = 0; i < 4; ++i)
      #pragma unroll
      for (int n = 0; n < 2; ++n)
        #pragma unroll
        for (int kk = 0; kk < 2; ++kk)
          acc[4 + i][n] = __builtin_amdgcn_mfma_f32_16x16x32_bf16(af[i][kk], bf[n][kk], acc[4 + i][n], 0, 0, 0);
    __builtin_amdgcn_s_setprio(0);
    __builtin_amdgcn_s_barrier();

    // ---- P3: (A-hi x B-hi). no reads ----
    if (pf) { STAGE(1, t + 1, nxt); asm volatile("s_waitcnt vmcnt(4)" ::: "memory"); }
    __builtin_amdgcn_s_barrier();
    __builtin_amdgcn_s_setprio(1);
    #pragma unroll
    for (int i = 0; i < 4; ++i)
      #pragma unroll
      for (int n = 0; n < 2; ++n)
        #pragma unroll
        for (int kk = 0; kk < 2; ++kk)
          acc[4 + i][2 + n] = __builtin_amdgcn_mfma_f32_16x16x32_bf16(af[i][kk], bf[2 + n][kk], acc[4 + i][2 + n], 0, 0, 0);
    __builtin_amdgcn_s_setprio(0);
    __builtin_amdgcn_s_barrier();
  }

  // epilogue: +bias, C-write (C/D layout: col=lane&15, row=(lane>>4)*4+q)
  #pragma unroll
  for (int ni = 0; ni < 4; ++ni) {
    int col = n0 + (ni & 1) * 16 + wn * 32 + (ni >> 1) * 128 + (lane & 15);
    float bv = bias[col];
    #pragma unroll
    for (int mi = 0; mi < 8; ++mi) {
      int row0 = m0 + (mi & 3) * 16 + wm * 64 + (mi >> 2) * 128 + ((lane >> 4) << 2);
      #pragma unroll
      for (int q = 0; q < 4; ++q) {
        float v = acc[mi][ni][q] + bv;
        if constexpr (OUT_BF16)
          ((ushort*)Cv)[(size_t)(row0 + q) * N + col] = f2b(v);
        else
          ((float*)Cv)[(size_t)(row0 + q) * N + col] = v;
      }
    }
  }
}

// --------- fallback GEMM (round-1, fp32 reg-staged, XOR-swizzled LDS) ------
template<bool A_IS_BF16, bool OUT_BF16>
__global__ __launch_bounds__(256)
void gemm_bt(const void* __restrict__ Av, const float* __restrict__ B,
             const float* __restrict__ bias, void* __restrict__ Cv,
             int M, int N, int K)
{
  __shared__ ushort As[BM * BK];
  __shared__ ushort Bs[BN * BK];

  const int tid  = threadIdx.x;
  const int lane = tid & 63;
  const int wid  = tid >> 6;
  const int wr   = wid >> 1;
  const int wc   = wid & 1;
  const int m0   = blockIdx.y * BM;
  const int n0   = blockIdx.x * BN;

  f32x4 acc[4][4] = {};

  const int r   = tid >> 1;
  const int seg = (tid & 1) * 32;

  for (int k0 = 0; k0 < K; k0 += BK) {
    {
      ushort tmp[32];
      if constexpr (A_IS_BF16) {
        const ushort* gA = (const ushort*)Av + (size_t)(m0 + r) * K + k0 + seg;
        #pragma unroll
        for (int u = 0; u < 4; ++u)
          *reinterpret_cast<uint4*>(&tmp[u * 8]) =
              *reinterpret_cast<const uint4*>(gA + u * 8);
      } else {
        const float* gA = (const float*)Av + (size_t)(m0 + r) * K + k0 + seg;
        #pragma unroll
        for (int u = 0; u < 8; ++u) {
          float4 f = *reinterpret_cast<const float4*>(gA + u * 4);
          tmp[u * 4 + 0] = f2b(f.x); tmp[u * 4 + 1] = f2b(f.y);
          tmp[u * 4 + 2] = f2b(f.z); tmp[u * 4 + 3] = f2b(f.w);
        }
      }
      #pragma unroll
      for (int s4 = 0; s4 < 4; ++s4) {
        int slot = (seg >> 3) + s4;
        int byte = r * 128 + ((slot ^ (r & 7)) << 4);
        *reinterpret_cast<uint4*>((char*)As + byte) =
            *reinterpret_cast<uint4*>(&tmp[s4 * 8]);
      }
    }
    {
      const float* gB = B + (size_t)(n0 + r) * K + k0 + seg;
      ushort tmp[32];
      #pragma unroll
      for (int u = 0; u < 8; ++u) {
        float4 f = *reinterpret_cast<const float4*>(gB + u * 4);
        tmp[u * 4 + 0] = f2b(f.x); tmp[u * 4 + 1] = f2b(f.y);
        tmp[u * 4 + 2] = f2b(f.z); tmp[u * 4 + 3] = f2b(f.w);
      }
      #pragma unroll
      for (int s4 = 0; s4 < 4; ++s4) {
        int slot = (seg >> 3) + s4;
        int byte = r * 128 + ((slot ^ (r & 7)) << 4);
        *reinterpret_cast<uint4*>((char*)Bs + byte) =
            *reinterpret_cast<uint4*>(&tmp[s4 * 8]);
      }
    }
    __syncthreads();

    #pragma unroll
    for (int kk = 0; kk < 2; ++kk) {
      const int kbase = kk * 32 + ((lane >> 4) << 3);
      const int slot  = kbase >> 3;
      bf16x8 af[4], bfr[4];
      #pragma unroll
      for (int mi = 0; mi < 4; ++mi) {
        int row = wr * 64 + mi * 16 + (lane & 15);
        af[mi] = *reinterpret_cast<const bf16x8*>(
            (const char*)As + row * 128 + ((slot ^ (row & 7)) << 4));
      }
      #pragma unroll
      for (int ni = 0; ni < 4; ++ni) {
        int row = wc * 64 + ni * 16 + (lane & 15);
        bfr[ni] = *reinterpret_cast<const bf16x8*>(
            (const char*)Bs + row * 128 + ((slot ^ (row & 7)) << 4));
      }
      #pragma unroll
      for (int mi = 0; mi < 4; ++mi)
        #pragma unroll
        for (int ni = 0; ni < 4; ++ni)
          acc[mi][ni] = __builtin_amdgcn_mfma_f32_16x16x32_bf16(
              af[mi], bfr[ni], acc[mi][ni], 0, 0, 0);
    }
    __syncthreads();
  }

  #pragma unroll
  for (int ni = 0; ni < 4; ++ni) {
    int col = n0 + wc * 64 + ni * 16 + (lane & 15);
    float bv = bias[col];
    #pragma unroll
    for (int mi = 0; mi < 4; ++mi) {
      int row0 = m0 + wr * 64 + mi * 16 + ((lane >> 4) << 2);
      #pragma unroll
      for (int q = 0; q < 4; ++q) {
        float v = acc[mi][ni][q] + bv;
        if constexpr (OUT_BF16)
          ((ushort*)Cv)[(size_t)(row0 + q) * N + col] = f2b(v);
        else
          ((float*)Cv)[(size_t)(row0 + q) * N + col] = v;
      }
    }
  }
}

// ---------------- per-position attention across heads ----------------------
__global__ __launch_bounds__(256)
void attn_kernel(const ushort* __restrict__ Q, const ushort* __restrict__ Kh,
                 const ushort* __restrict__ V, ushort* __restrict__ O)
{
  __shared__ float smem[4][3][16][68];   // [wave][Q/K/V][head][64+pad]
  const int tid  = threadIdx.x;
  const int wid  = tid >> 6;
  const int lane = tid & 63;
  const size_t p = (size_t)blockIdx.x * 4 + wid;

  {
    const ushort* srcs[3] = { Q + p * 1024, Kh + p * 1024, V + p * 1024 };
    const int i  = lane >> 2;
    const int d0 = (lane & 3) * 16;
    #pragma unroll
    for (int m = 0; m < 3; ++m) {
      const ushort* s = srcs[m] + lane * 16;
      ushort u[16];
      *reinterpret_cast<uint4*>(&u[0]) = *reinterpret_cast<const uint4*>(s);
      *reinterpret_cast<uint4*>(&u[8]) = *reinterpret_cast<const uint4*>(s + 8);
      #pragma unroll
      for (int e = 0; e < 16; ++e) smem[wid][m][i][d0 + e] = bf2f(u[e]);
    }
  }
  __syncthreads();

  const int i  = lane >> 2;
  const int jg = lane & 3;
  const float* qrow = smem[wid][0][i];
  const float* k0r = smem[wid][1][jg * 4 + 0];
  const float* k1r = smem[wid][1][jg * 4 + 1];
  const float* k2r = smem[wid][1][jg * 4 + 2];
  const float* k3r = smem[wid][1][jg * 4 + 3];

  float s0 = 0.f, s1 = 0.f, s2 = 0.f, s3 = 0.f;
  #pragma unroll
  for (int d = 0; d < 64; ++d) {
    float qv = qrow[d];
    s0 += qv * k0r[d]; s1 += qv * k1r[d];
    s2 += qv * k2r[d]; s3 += qv * k3r[d];
  }
  const float scale = 0.125f;  // 1/sqrt(64)
  s0 *= scale; s1 *= scale; s2 *= scale; s3 *= scale;

  float mx = fmaxf(fmaxf(s0, s1), fmaxf(s2, s3));
  mx = fmaxf(mx, __shfl_xor(mx, 1));
  mx = fmaxf(mx, __shfl_xor(mx, 2));
  float e0 = __expf(s0 - mx), e1 = __expf(s1 - mx);
  float e2 = __expf(s2 - mx), e3 = __expf(s3 - mx);
  float sum = e0 + e1 + e2 + e3;
  sum += __shfl_xor(sum, 1);
  sum += __shfl_xor(sum, 2);
  float inv = 1.0f / sum;
  e0 *= inv; e1 *= inv; e2 *= inv; e3 *= inv;

  const float* v0r = smem[wid][2][jg * 4 + 0];
  const float* v1r = smem[wid][2][jg * 4 + 1];
  const float* v2r = smem[wid][2][jg * 4 + 2];
  const float* v3r = smem[wid][2][jg * 4 + 3];
  ushort* orow = O + p * 1024 + i * 64;

  #pragma unroll
  for (int c = 0; c < 4; ++c) {
    float po[16];
    #pragma unroll
    for (int dd = 0; dd < 16; ++dd) {
      int d = c * 16 + dd;
      po[dd] = e0 * v0r[d] + e1 * v1r[d] + e2 * v2r[d] + e3 * v3r[d];
    }
    #pragma unroll
    for (int dd = 0; dd < 16; ++dd) {
      po[dd] += __shfl_xor(po[dd], 1);
      po[dd] += __shfl_xor(po[dd], 2);
    }
    if (jg == c) {
      #pragma unroll
      for (int dd = 0; dd < 16; ++dd) orow[c * 16 + dd] = f2b(po[dd]);
    }
  }
}

extern "C" void kernel_launch(void* const* d_in, const int* in_sizes, int n_in,
                              void* d_out, int out_size, void* d_ws, size_t ws_size,
                              hipStream_t stream)
{
  const float* query = (const float*)d_in[0];
  const float* key_  = (const float*)d_in[1];
  const float* value = (const float*)d_in[2];
  const float* wq_w  = (const float*)d_in[3];
  const float* wq_b  = (const float*)d_in[4];
  const float* wk_w  = (const float*)d_in[5];
  const float* wk_b  = (const float*)d_in[6];
  const float* wv_w  = (const float*)d_in[7];
  const float* wv_b  = (const float*)d_in[8];
  const float* fo_w  = (const float*)d_in[9];
  const float* fo_b  = (const float*)d_in[10];

  const int K = 1024, N = 1024;
  const int M = in_sizes[0] / K;       // 16384
  const size_t slot = (size_t)M * N;
  const size_t wsl  = (size_t)N * K;
  const size_t need = (4 * slot + 4 * wsl) * sizeof(ushort);  // 136 MiB

  if (ws_size >= need && (M % 256) == 0) {
    hipFuncSetAttribute(reinterpret_cast<const void*>(gemm8p<true>),
                        hipFuncAttributeMaxDynamicSharedMemorySize, 131072);
    hipFuncSetAttribute(reinterpret_cast<const void*>(gemm8p<false>),
                        hipFuncAttributeMaxDynamicSharedMemorySize, 131072);

    ushort* S0 = (ushort*)d_ws;           // recycled input slot, then attn out
    ushort* S1 = S0 + slot;               // Q projection
    ushort* S2 = S1 + slot;               // K projection
    ushort* S3 = S2 + slot;               // V projection
    ushort* Wq = S3 + slot;
    ushort* Wk = Wq + wsl;
    ushort* Wv = Wk + wsl;
    ushort* Wo = Wv + wsl;

    const int n8w = (int)(wsl / 8);
    const int n8s = (int)(slot / 8);
    dim3 g8(N / 256, M / 256);            // (4, 64) = 256 blocks
    dim3 b8(512);

    cvt_f32_bf16<<<dim3((n8w + 255) / 256), dim3(256), 0, stream>>>(wq_w, Wq, n8w);
    cvt_f32_bf16<<<dim3((n8w + 255) / 256), dim3(256), 0, stream>>>(wk_w, Wk, n8w);
    cvt_f32_bf16<<<dim3((n8w + 255) / 256), dim3(256), 0, stream>>>(wv_w, Wv, n8w);
    cvt_f32_bf16<<<dim3((n8w + 255) / 256), dim3(256), 0, stream>>>(fo_w, Wo, n8w);

    cvt_f32_bf16<<<dim3((n8s + 255) / 256), dim3(256), 0, stream>>>(query, S0, n8s);
    gemm8p<true><<<g8, b8, 131072, stream>>>(S0, Wq, wq_b, S1, M, N, K);
    cvt_f32_bf16<<<dim3((n8s + 255) / 256), dim3(256), 0, stream>>>(key_, S0, n8s);
    gemm8p<true><<<g8, b8, 131072, stream>>>(S0, Wk, wk_b, S2, M, N, K);
    cvt_f32_bf16<<<dim3((n8s + 255) / 256), dim3(256), 0, stream>>>(value, S0, n8s);
    gemm8p<true><<<g8, b8, 131072, stream>>>(S0, Wv, wv_b, S3, M, N, K);

    attn_kernel<<<dim3(M / 4), dim3(256), 0, stream>>>(S1, S2, S3, S0);
    gemm8p<false><<<g8, b8, 131072, stream>>>(S0, Wo, fo_b, d_out, M, N, K);
  } else {
    dim3 grid(N / BN, M / BM);
    ushort* Qb = (ushort*)d_ws;
    ushort* Kb = Qb + slot;
    ushort* Vb = Kb + slot;
    ushort* Ob = Vb + slot;
    gemm_bt<false, true><<<grid, dim3(256), 0, stream>>>(query, wq_w, wq_b, Qb, M, N, K);
    gemm_bt<false, true><<<grid, dim3(256), 0, stream>>>(key_,  wk_w, wk_b, Kb, M, N, K);
    gemm_bt<false, true><<<grid, dim3(256), 0, stream>>>(value, wv_w, wv_b, Vb, M, N, K);
    attn_kernel<<<dim3(M / 4), dim3(256), 0, stream>>>(Qb, Kb, Vb, Ob);
    gemm_bt<true, false><<<grid, dim3(256), 0, stream>>>(Ob, fo_w, fo_b, d_out, M, N, K);
  }
}